// Round 9
// baseline (187.043 us; speedup 1.0000x reference)
//
#include <hip/hip_runtime.h>
#include <hip/hip_bf16.h>
#include <stdint.h>

// B=2, S=4096, D=512, H=8, dk=64. fp32 in/out, bf16 MFMA internals.
// R20 (on R19, attn 71.5us): counters show MFMA-need 52% + VALU-need 43%
// executing strictly serially (sum=95% ~ measured). The 2 resident blocks
// per CU are phase-locked (identical code, same start, no symmetry break),
// so cross-wave MFMA/VALU dual-issue (m114) never materializes. Fix: ONE
// s_sleep(5) (~320cyc ~ half tile body) at entry for parity blocks
// (((lin>>3)^(lin>>8))&1 flips for both plausible co-residency pairings)
// -> anti-phase blocks -> wave A's MFMA-burst pipe stall overlaps wave B's
// exp2/pack VALU burst. Math bit-identical to R19.

typedef __bf16 bf16;
typedef __attribute__((ext_vector_type(8))) __bf16 bf16x8;
typedef __attribute__((ext_vector_type(4))) __bf16 bf16x4;
typedef __attribute__((ext_vector_type(4))) float f32x4;
typedef __attribute__((ext_vector_type(4))) unsigned int u32x4;

#define LOG2E 1.44269504088896340736f
// Swizzled elem offset of an 8-elem group in a [rows][64] bf16 LDS tile.
#define SW(row, grp) (((row) << 6) + ((((grp) ^ ((row) & 7))) << 3))

// pack two f32 into (bf16(hi)<<16)|bf16(lo) by hi-16 truncation (RTZ)
__device__ __forceinline__ unsigned int pkbf16(float lo, float hi) {
  return __builtin_amdgcn_perm(__builtin_bit_cast(unsigned int, hi),
                               __builtin_bit_cast(unsigned int, lo),
                               0x07060302u);
}

// async global->LDS, 16B per lane; LDS dest = base + lane*16 (linear).
__device__ __forceinline__ void gl_lds16(const bf16* g, bf16* l) {
  __builtin_amdgcn_global_load_lds(
      (const __attribute__((address_space(1))) void*)g,
      (__attribute__((address_space(3))) void*)l, 16, 0, 0);
}

// ---------------------------------------------------------------- LayerNorm
__global__ __launch_bounds__(256) void ln_kernel(
    const float* __restrict__ x, const float* __restrict__ gamma,
    const float* __restrict__ beta, bf16* __restrict__ h) {
  int wave = threadIdx.x >> 6, lane = threadIdx.x & 63;
  int row = blockIdx.x * 4 + wave;                 // 8192 rows
  const float* xr = x + (size_t)row * 512 + lane * 8;
  f32x4 v0 = *(const f32x4*)xr;
  f32x4 v1 = *(const f32x4*)(xr + 4);
  float f[8], s = 0.f, s2 = 0.f;
#pragma unroll
  for (int i = 0; i < 4; ++i) { f[i] = v0[i]; f[4 + i] = v1[i]; }
#pragma unroll
  for (int i = 0; i < 8; ++i) { s += f[i]; s2 += f[i] * f[i]; }
#pragma unroll
  for (int off = 1; off < 64; off <<= 1) {
    s  += __shfl_xor(s, off, 64);
    s2 += __shfl_xor(s2, off, 64);
  }
  float mu  = s * (1.f / 512.f);
  float var = s2 * (1.f / 512.f) - mu * mu;
  float rstd = rsqrtf(var + 1e-5f);
  f32x4 g0 = *(const f32x4*)(gamma + lane * 8);
  f32x4 g1 = *(const f32x4*)(gamma + lane * 8 + 4);
  f32x4 b0 = *(const f32x4*)(beta + lane * 8);
  f32x4 b1 = *(const f32x4*)(beta + lane * 8 + 4);
  bf16x8 o;
#pragma unroll
  for (int i = 0; i < 4; ++i) {
    o[i]     = (bf16)((f[i]     - mu) * rstd * g0[i] + b0[i]);
    o[4 + i] = (bf16)((f[4 + i] - mu) * rstd * g1[i] + b1[i]);
  }
  *(bf16x8*)(h + (size_t)row * 512 + lane * 8) = o;
}

// ------------------------------------------------------------- QKV GEMM
__global__ __launch_bounds__(256) void qkv_kernel(
    const bf16* __restrict__ h, const float* __restrict__ wq,
    const float* __restrict__ wk, const float* __restrict__ wv,
    bf16* __restrict__ Qg, bf16* __restrict__ Kg, bf16* __restrict__ Vtg) {
  __shared__ bf16 smemq[2 * 128 * 64];   // As | Bs (contiguous for V alias)
  bf16* As = smemq;
  bf16* Bs = smemq + 128 * 64;
  int tid = threadIdx.x, wave = tid >> 6, lane = tid & 63;
  int wm = wave >> 1, wn = wave & 1, quad = lane >> 4, l15 = lane & 15;
  // XCD-chunked swizzle: lin%8 = XCD (round-robin dispatch). Give XCD k the
  // 96 blocks covering mtiles [8k, 8k+8) x all 12 (wsel,nb).
  int lin = blockIdx.x + (blockIdx.y << 6);        // 0..767
  int xcd = lin & 7, idx = lin >> 3;               // 96 blocks per XCD
  int mtile = xcd * 8 + idx / 12;                  // 0..63
  int yy = idx % 12;
  int wsel = yy >> 2;                              // 0=q 1=k 2=v
  int nb = yy & 3;
  const float* W = (wsel == 0) ? wq : (wsel == 1 ? wk : wv);
  const bf16*  Abase = h + (size_t)mtile * 128 * 512;
  const float* Bbase = W + (size_t)nb * 128 * 512;
  f32x4 acc[4][4];
#pragma unroll
  for (int i = 0; i < 4; ++i)
#pragma unroll
    for (int j = 0; j < 4; ++j) acc[i][j] = (f32x4){0.f, 0.f, 0.f, 0.f};

  int srow = tid >> 3, grp = tid & 7, scol = grp * 8;
  bf16x8 ar[4];
  f32x4 br0[4], br1[4];
#pragma unroll
  for (int k = 0; k < 4; ++k) {                 // prologue: tile 0 loads
    int rr = srow + k * 32;
    ar[k]  = *(const bf16x8*)(Abase + (size_t)rr * 512 + scol);
    br0[k] = *(const f32x4*)(Bbase + (size_t)rr * 512 + scol);
    br1[k] = *(const f32x4*)(Bbase + (size_t)rr * 512 + scol + 4);
  }
  for (int k0 = 0; k0 < 512; k0 += 64) {
#pragma unroll
    for (int k = 0; k < 4; ++k) {               // regs -> LDS
      int rr = srow + k * 32;
      int w = SW(rr, grp);
      *(bf16x8*)(As + w) = ar[k];
      bf16x8 wb;
#pragma unroll
      for (int j = 0; j < 4; ++j) { wb[j] = (bf16)br0[k][j]; wb[4 + j] = (bf16)br1[k][j]; }
      *(bf16x8*)(Bs + w) = wb;
    }
    __syncthreads();
    if (k0 < 448) {                             // prefetch next tile
#pragma unroll
      for (int k = 0; k < 4; ++k) {
        int rr = srow + k * 32;
        ar[k]  = *(const bf16x8*)(Abase + (size_t)rr * 512 + k0 + 64 + scol);
        br0[k] = *(const f32x4*)(Bbase + (size_t)rr * 512 + k0 + 64 + scol);
        br1[k] = *(const f32x4*)(Bbase + (size_t)rr * 512 + k0 + 64 + scol + 4);
      }
    }
#pragma unroll
    for (int c = 0; c < 2; ++c) {
      bf16x8 af[4], bw[4];
#pragma unroll
      for (int mt = 0; mt < 4; ++mt)
        af[mt] = *(const bf16x8*)(As + SW(wm * 64 + mt * 16 + l15, c * 4 + quad));
#pragma unroll
      for (int nt = 0; nt < 4; ++nt)
        bw[nt] = *(const bf16x8*)(Bs + SW(wn * 64 + nt * 16 + l15, c * 4 + quad));
#pragma unroll
      for (int mt = 0; mt < 4; ++mt)
#pragma unroll
        for (int nt = 0; nt < 4; ++nt)
          acc[mt][nt] = __builtin_amdgcn_mfma_f32_16x16x32_bf16(
              bw[nt], af[mt], acc[mt][nt], 0, 0, 0);
    }
    __syncthreads();
  }
  // Q pre-scale folds softmax 1/sqrt(64) AND log2(e) for exp2-based softmax.
  if (wsel < 2) {
    float qscale = (wsel == 0) ? (0.125f * LOG2E) : 1.0f;
#pragma unroll
    for (int mt = 0; mt < 4; ++mt) {
      int m_g = mtile * 128 + wm * 64 + mt * 16 + l15;   // token
      int b = m_g >> 12, s = m_g & 4095;
#pragma unroll
      for (int nt = 0; nt < 4; ++nt) {
        int n_g = nb * 128 + wn * 64 + nt * 16 + quad * 4;  // feature
        int head = n_g >> 6, d = n_g & 63;
        f32x4 a = acc[mt][nt];
        bf16* dst = (wsel == 0 ? Qg : Kg) +
                    ((size_t)((b * 8 + head) * 4096 + s)) * 64 + d;
        bf16x4 pk;
#pragma unroll
        for (int r = 0; r < 4; ++r) pk[r] = (bf16)(a[r] * qscale);
        *(bf16x4*)dst = pk;
      }
    }
  } else {
    // V^T store in SLOT ORDER via LDS transpose. Vt[128 feat][128 tok]
    // (32KB alias), token col XOR-swizzled by (feat&7)<<3.
    // Slot p in each 64-key tile holds key k: p = g*8+t, g=pr*4+qd;
    // t<4 -> k = pr*32+qd*4+t ; t>=4 -> k = pr*32+16+qd*4+(t-4).
    bf16* Vt = smemq;
#pragma unroll
    for (int mt = 0; mt < 4; ++mt) {
      int t = wm * 64 + mt * 16 + l15;                     // token-local
#pragma unroll
      for (int nt = 0; nt < 4; ++nt) {
#pragma unroll
        for (int r = 0; r < 4; ++r) {
          int f = wn * 64 + nt * 16 + quad * 4 + r;        // feature-local
          Vt[f * 128 + (t ^ ((f & 7) << 3))] = (bf16)acc[mt][nt][r];
        }
      }
    }
    __syncthreads();
    int fr = tid >> 1, hf = tid & 1;
    int n_g = nb * 128 + fr;
    int head = n_g >> 6, d = n_g & 63;
    int bb = mtile >> 5;                                   // batch of block
    bf16* dst = Vtg + ((size_t)((bb * 8 + head) * 64 + d)) * 4096 +
                (mtile & 31) * 128 + hf * 64;
    int sx3 = (fr & 7) << 3;
#pragma unroll
    for (int g = 0; g < 8; ++g) {
      int pr = g >> 2, qd = g & 3;
      int tb = hf * 64 + pr * 32 + qd * 4;
      bf16x4 lo  = *(const bf16x4*)(Vt + fr * 128 + (tb ^ sx3));
      bf16x4 hi4 = *(const bf16x4*)(Vt + fr * 128 + ((tb + 16) ^ sx3));
      bf16x8 v;
#pragma unroll
      for (int j = 0; j < 4; ++j) { v[j] = lo[j]; v[4 + j] = hi4[j]; }
      *(bf16x8*)(dst + g * 8) = v;
    }
  }
}

// --------------------------------------------------------- Flash attention
// R12 structure: 4 waves = (qgrp 0/1) x (khalf 0/1). 64 q/wave, keys
// [khalf*2048,+2048) in 32 tiles of 64. K/V double-buffered (64KB), 1
// barrier/tile. Staging via global_load_lds w16 (pre-swizzled global
// source + linear LDS dest). R20: parity blocks sleep ~320cyc at entry to
// anti-phase the 2 resident blocks/CU (cross-wave MFMA/VALU dual issue).
__global__ __launch_bounds__(256, 2) void attn_kernel(
    const bf16* __restrict__ Qg, const bf16* __restrict__ Kg,
    const bf16* __restrict__ Vtg, bf16* __restrict__ Og) {
  __shared__ char smem[64 * 1024];
  bf16* KV = (bf16*)smem;               // [buf][khalf][K 4096 | V 4096]
  float* OL = (float*)smem;             // merge alias: 2x4096 f32
  float* Ll = (float*)(smem + 49152);   // merge l: 128 f32 (alias)

  int tid = threadIdx.x, wave = tid >> 6, lane = tid & 63;
  int quad = lane >> 4, l15 = lane & 15;
  int qgrp = wave & 1, khalf = wave >> 1;
  // XCD swizzle: XCD k serves bh pair {2k,2k+1}.
  int lin = blockIdx.x;                 // 0..511
  int bh = ((lin & 7) << 1) | ((lin >> 3) & 1);
  int q0 = (lin >> 4) * 128;
  int hi = bh & 7, bi = bh >> 3;
  const bf16* Kh  = Kg  + (size_t)bh * 4096 * 64;
  const bf16* Vth = Vtg + (size_t)bh * 64 * 4096;

  bf16x8 qf[4][2];   // Q pre-scaled by 0.125*LOG2E in qkv
#pragma unroll
  for (int mt = 0; mt < 4; ++mt)
#pragma unroll
    for (int c = 0; c < 2; ++c)
      qf[mt][c] = *(const bf16x8*)(
          Qg + ((size_t)bh * 4096 + q0 + qgrp * 64 + mt * 16 + l15) * 64 +
          c * 32 + quad * 8);

  f32x4 o_acc[4][4], lacc[4];
#pragma unroll
  for (int mt = 0; mt < 4; ++mt) {
    lacc[mt] = (f32x4){0.f, 0.f, 0.f, 0.f};
#pragma unroll
    for (int nt = 0; nt < 4; ++nt) o_acc[mt][nt] = (f32x4){0.f, 0.f, 0.f, 0.f};
  }
  const u32x4 onesu = {0x3F803F80u, 0x3F803F80u, 0x3F803F80u, 0x3F803F80u};
  const bf16x8 ones8 = __builtin_bit_cast(bf16x8, onesu);
  const f32x4 z4 = {0.f, 0.f, 0.f, 0.f};  // shared zero C-in for QK MFMAs

  // R20 desync: anti-phase the two co-resident blocks (lin vs lin+8 or
  // lin vs lin+256 both flip this parity). ~320 cyc = half a tile body.
  if (((lin >> 3) ^ (lin >> 8)) & 1) __builtin_amdgcn_s_sleep(5);

  // Staging: wave (qgrp,khalf) stages stream qgrp (0=K,1=V) of its khalf.
  // Pre-swizzled per-lane source so linear LDS dest = XOR-swizzled layout:
  // lane l covers LDS row lr = l>>3, physical grp l&7 -> content grp
  // lg = (l&7)^(lr&7).
  int key0 = khalf * 2048;
  int lr = lane >> 3, lg = (lane & 7) ^ (lr & 7);
  const bf16* gKb = Kh + ((size_t)key0 + lr) * 64 + lg * 8;   // +kt*4096+i*512
  const bf16* gVb = Vth + (size_t)lr * 4096 + key0 + lg * 8;  // +kt*64+i*32768
  bf16* myK = KV + khalf * 8192;        // dest in buf0
  bf16* myV = myK + 4096;

  if (qgrp == 0) {                       // tile 0 -> buf0
#pragma unroll
    for (int i = 0; i < 8; ++i) gl_lds16(gKb + i * 512, myK + i * 512);
  } else {
#pragma unroll
    for (int i = 0; i < 8; ++i)
      gl_lds16(gVb + (size_t)i * 32768, myV + i * 512);
  }
  __syncthreads();                       // drains vmcnt: tile 0 visible

  for (int kt = 0; kt < 32; ++kt) {
    int cur = kt & 1, nxt = cur ^ 1;
    bf16* Ksw = KV + cur * 16384 + khalf * 8192;
    bf16* Vsw = Ksw + 4096;
    if (kt < 31) {                       // issue tile kt+1 -> other buffer
      if (qgrp == 0) {
        const bf16* src = gKb + (size_t)(kt + 1) * 4096;
        bf16* d = myK + nxt * 16384;
#pragma unroll
        for (int i = 0; i < 8; ++i) gl_lds16(src + i * 512, d + i * 512);
      } else {
        const bf16* src = gVb + (kt + 1) * 64;
        bf16* d = myV + nxt * 16384;
#pragma unroll
        for (int i = 0; i < 8; ++i)
          gl_lds16(src + (size_t)i * 32768, d + i * 512);
      }
    }
    // ---- compute tile kt (R12 verbatim) ----
    bf16x8 kf[8];
#pragma unroll
    for (int kb = 0; kb < 4; ++kb)
#pragma unroll
      for (int c = 0; c < 2; ++c)
        kf[kb * 2 + c] = *(const bf16x8*)(Ksw + SW(kb * 16 + l15, c * 4 + quad));
    bf16x8 vf8[2][4];
#pragma unroll
    for (int pr = 0; pr < 2; ++pr)
#pragma unroll
      for (int nt = 0; nt < 4; ++nt)
        vf8[pr][nt] = *(const bf16x8*)(Vsw + SW(nt * 16 + l15, pr * 4 + quad));
#pragma unroll
    for (int mt = 0; mt < 4; ++mt) {
      f32x4 st[4];
#pragma unroll
      for (int kb = 0; kb < 4; ++kb)     // c=0 slab: shared zero C-in
        st[kb] = __builtin_amdgcn_mfma_f32_16x16x32_bf16(
            kf[kb * 2], qf[mt][0], z4, 0, 0, 0);
#pragma unroll
      for (int kb = 0; kb < 4; ++kb)     // c=1 slab accumulates
        st[kb] = __builtin_amdgcn_mfma_f32_16x16x32_bf16(
            kf[kb * 2 + 1], qf[mt][1], st[kb], 0, 0, 0);
#pragma unroll
      for (int pr = 0; pr < 2; ++pr) {
        float ea[4], eb[4];
#pragma unroll
        for (int r = 0; r < 4; ++r) {
          ea[r] = __builtin_amdgcn_exp2f(st[pr * 2][r]);
          eb[r] = __builtin_amdgcn_exp2f(st[pr * 2 + 1][r]);
        }
        u32x4 pw = {pkbf16(ea[0], ea[1]), pkbf16(ea[2], ea[3]),
                    pkbf16(eb[0], eb[1]), pkbf16(eb[2], eb[3])};
        bf16x8 pk8 = __builtin_bit_cast(bf16x8, pw);
#pragma unroll
        for (int nt = 0; nt < 4; ++nt)
          o_acc[mt][nt] = __builtin_amdgcn_mfma_f32_16x16x32_bf16(
              vf8[pr][nt], pk8, o_acc[mt][nt], 0, 0, 0);
        lacc[mt] = __builtin_amdgcn_mfma_f32_16x16x32_bf16(
            ones8, pk8, lacc[mt], 0, 0, 0);
      }
    }
    __syncthreads();   // drains vmcnt (kt+1 writes) + lgkm; swap buffers
  }
  // ---- merge the two key-halves (pure addition; no-max softmax) ----
  if (khalf == 1) {
    float* dst = OL + qgrp * 4096;
#pragma unroll
    for (int mt = 0; mt < 4; ++mt) {
#pragma unroll
      for (int nt = 0; nt < 4; ++nt) {
        int row = mt * 16 + l15;
        int g = nt * 4 + quad;
        int gs = (g & 8) | ((g ^ row) & 7);
        *(f32x4*)(&dst[row * 64 + gs * 4]) = o_acc[mt][nt];
      }
      if (quad == 0) Ll[qgrp * 64 + mt * 16 + l15] = lacc[mt][0];
    }
  }
  __syncthreads();
  if (khalf == 0) {
    const float* src = OL + qgrp * 4096;
#pragma unroll
    for (int mt = 0; mt < 4; ++mt) {
      float lt = lacc[mt][0] + Ll[qgrp * 64 + mt * 16 + l15];
      float inv = 1.0f / lt;
      int q = q0 + qgrp * 64 + mt * 16 + l15;
#pragma unroll
      for (int nt = 0; nt < 4; ++nt) {
        int row = mt * 16 + l15;
        int g = nt * 4 + quad;
        int gs = (g & 8) | ((g ^ row) & 7);
        f32x4 o = *(const f32x4*)(&src[row * 64 + gs * 4]);
        bf16x4 pk;
#pragma unroll
        for (int r = 0; r < 4; ++r)
          pk[r] = (bf16)((o[r] + o_acc[mt][nt][r]) * inv);
        *(bf16x4*)(&Og[((size_t)bi * 4096 + q) * 512 + hi * 64 + nt * 16 +
                       quad * 4]) = pk;
      }
    }
  }
}

// ----------------------------------------------- out = A @ Wo^T + bo + x
__global__ __launch_bounds__(256) void proj_kernel(
    const bf16* __restrict__ A, const float* __restrict__ Wo,
    const float* __restrict__ bo, const float* __restrict__ x,
    float* __restrict__ out) {
  __shared__ bf16 As[128 * 64];
  __shared__ bf16 Bs[128 * 64];
  int tid = threadIdx.x, wave = tid >> 6, lane = tid & 63;
  int wm = wave >> 1, wn = wave & 1, quad = lane >> 4, l15 = lane & 15;
  int mtile = blockIdx.x, nb = blockIdx.y;
  const bf16*  Abase = A + (size_t)mtile * 128 * 512;
  const float* Bbase = Wo + (size_t)nb * 128 * 512;
  f32x4 acc[4][4];
#pragma unroll
  for (int i = 0; i < 4; ++i)
#pragma unroll
    for (int j = 0; j < 4; ++j) acc[i][j] = (f32x4){0.f, 0.f, 0.f, 0.f};

  int srow = tid >> 3, grp = tid & 7, scol = grp * 8;
  bf16x8 ar[4];
  f32x4 br0[4], br1[4];
#pragma unroll
  for (int k = 0; k < 4; ++k) {
    int rr = srow + k * 32;
    ar[k]  = *(const bf16x8*)(Abase + (size_t)rr * 512 + scol);
    br0[k] = *(const f32x4*)(Bbase + (size_t)rr * 512 + scol);
    br1[k] = *(const f32x4*)(Bbase + (size_t)rr * 512 + scol + 4);
  }
  for (int k0 = 0; k0 < 512; k0 += 64) {
#pragma unroll
    for (int k = 0; k < 4; ++k) {
      int rr = srow + k * 32;
      int w = SW(rr, grp);
      *(bf16x8*)(As + w) = ar[k];
      bf16x8 wb;
#pragma unroll
      for (int j = 0; j < 4; ++j) { wb[j] = (bf16)br0[k][j]; wb[4 + j] = (bf16)br1[k][j]; }
      *(bf16x8*)(Bs + w) = wb;
    }
    __syncthreads();
    if (k0 < 448) {
#pragma unroll
      for (int k = 0; k < 4; ++k) {
        int rr = srow + k * 32;
        ar[k]  = *(const bf16x8*)(Abase + (size_t)rr * 512 + k0 + 64 + scol);
        br0[k] = *(const f32x4*)(Bbase + (size_t)rr * 512 + k0 + 64 + scol);
        br1[k] = *(const f32x4*)(Bbase + (size_t)rr * 512 + k0 + 64 + scol + 4);
      }
    }
#pragma unroll
    for (int c = 0; c < 2; ++c) {
      bf16x8 af[4], bw[4];
#pragma unroll
      for (int mt = 0; mt < 4; ++mt)
        af[mt] = *(const bf16x8*)(As + SW(wm * 64 + mt * 16 + l15, c * 4 + quad));
#pragma unroll
      for (int nt = 0; nt < 4; ++nt)
        bw[nt] = *(const bf16x8*)(Bs + SW(wn * 64 + nt * 16 + l15, c * 4 + quad));
#pragma unroll
      for (int mt = 0; mt < 4; ++mt)
#pragma unroll
        for (int nt = 0; nt < 4; ++nt)
          acc[mt][nt] = __builtin_amdgcn_mfma_f32_16x16x32_bf16(
              bw[nt], af[mt], acc[mt][nt], 0, 0, 0);
    }
    __syncthreads();
  }
#pragma unroll
  for (int mt = 0; mt < 4; ++mt) {
    int m_g = mtile * 128 + wm * 64 + mt * 16 + l15;
#pragma unroll
    for (int nt = 0; nt < 4; ++nt) {
      int n_g = nb * 128 + wn * 64 + nt * 16 + quad * 4;
      f32x4 a = acc[mt][nt];
      f32x4 xr = *(const f32x4*)(x + (size_t)m_g * 512 + n_g);
      f32x4 bb = *(const f32x4*)(bo + n_g);
      f32x4 o;
#pragma unroll
      for (int r = 0; r < 4; ++r)
        o[r] = a[r] + bb[r] + xr[r];
      *(f32x4*)(out + (size_t)m_g * 512 + n_g) = o;
    }
  }
}

extern "C" void kernel_launch(void* const* d_in, const int* in_sizes, int n_in,
                              void* d_out, int out_size, void* d_ws, size_t ws_size,
                              hipStream_t stream) {
  const float* x     = (const float*)d_in[0];
  const float* wq    = (const float*)d_in[1];
  const float* wk    = (const float*)d_in[2];
  const float* wv    = (const float*)d_in[3];
  const float* wo    = (const float*)d_in[4];
  const float* bo    = (const float*)d_in[5];
  const float* gamma = (const float*)d_in[6];
  const float* beta  = (const float*)d_in[7];
  float* out = (float*)d_out;
  char* ws = (char*)d_ws;
  const size_t SZ = (size_t)8192 * 512 * sizeof(bf16);  // 8 MB
  bf16* h   = (bf16*)(ws);          // aliased with Ao (h dead before attn)
  bf16* Ao  = (bf16*)(ws);
  bf16* Qg  = (bf16*)(ws + SZ);
  bf16* Kg  = (bf16*)(ws + 2 * SZ);
  bf16* Vtg = (bf16*)(ws + 3 * SZ);

  ln_kernel<<<2048, 256, 0, stream>>>(x, gamma, beta, h);
  qkv_kernel<<<dim3(64, 12), 256, 0, stream>>>(h, wq, wk, wv, Qg, Kg, Vtg);
  attn_kernel<<<512, 256, 0, stream>>>(Qg, Kg, Vtg, Ao);
  proj_kernel<<<dim3(64, 4), 256, 0, stream>>>(Ao, wo, bo, x, out);
}

// Round 10
// 176.639 us; speedup vs baseline: 1.0589x; 1.0589x over previous
//
#include <hip/hip_runtime.h>
#include <hip/hip_bf16.h>
#include <stdint.h>

// B=2, S=4096, D=512, H=8, dk=64. fp32 in/out, bf16 MFMA internals.
// R21 (on R19=best, attn 71.5us): R20 desync refuted (flat) -> attn is
// near its serial-sum floor; attack the other ~114us. qkv's staging does
// 8 f32->bf16 scalar converts + 2 f32x4 loads + ds_writes per thread per
// k-tile (re-converting each weight tile 64x). Fix (the R19/m193 lever):
//  - ln's grid grows +512 blocks that pre-convert wq/wk/wv/wo -> bf16
//    workspace buffer ONCE (same RNE cast -> bit-identical outputs).
//  - qkv + proj staging -> double-buffered global_load_lds w16 with
//    pre-swizzled global sources (same SW-layout algebra as R19 attn:
//    physical grp pg holds content grp pg^(row&7)). Zero staging VALU.
//  - attn = R19 verbatim (R20 sleep removed).

typedef __bf16 bf16;
typedef __attribute__((ext_vector_type(8))) __bf16 bf16x8;
typedef __attribute__((ext_vector_type(4))) __bf16 bf16x4;
typedef __attribute__((ext_vector_type(4))) float f32x4;
typedef __attribute__((ext_vector_type(4))) unsigned int u32x4;

#define LOG2E 1.44269504088896340736f
// Swizzled elem offset of an 8-elem group in a [rows][64] bf16 LDS tile.
#define SW(row, grp) (((row) << 6) + ((((grp) ^ ((row) & 7))) << 3))

// pack two f32 into (bf16(hi)<<16)|bf16(lo) by hi-16 truncation (RTZ)
__device__ __forceinline__ unsigned int pkbf16(float lo, float hi) {
  return __builtin_amdgcn_perm(__builtin_bit_cast(unsigned int, hi),
                               __builtin_bit_cast(unsigned int, lo),
                               0x07060302u);
}

// async global->LDS, 16B per lane; LDS dest = base (wave-uniform) + lane*16.
__device__ __forceinline__ void gl_lds16(const bf16* g, bf16* l) {
  __builtin_amdgcn_global_load_lds(
      (const __attribute__((address_space(1))) void*)g,
      (__attribute__((address_space(3))) void*)l, 16, 0, 0);
}

// ------------------------------------- LayerNorm + weight bf16 pre-convert
__global__ __launch_bounds__(256) void ln_kernel(
    const float* __restrict__ x, const float* __restrict__ gamma,
    const float* __restrict__ beta, bf16* __restrict__ h,
    const float* __restrict__ wq, const float* __restrict__ wk,
    const float* __restrict__ wv, const float* __restrict__ wo,
    bf16* __restrict__ wb) {
  if (blockIdx.x >= 2048) {              // weight convert: 512 blocks
    int cblk = blockIdx.x - 2048;        // 0..511; 128 blocks per matrix
    int m = cblk >> 7;
    int off = (cblk & 127) * 2048 + threadIdx.x * 8;
    const float* src = (m == 0 ? wq : m == 1 ? wk : m == 2 ? wv : wo) + off;
    f32x4 a = *(const f32x4*)src;
    f32x4 b = *(const f32x4*)(src + 4);
    bf16x8 o;
#pragma unroll
    for (int j = 0; j < 4; ++j) { o[j] = (bf16)a[j]; o[4 + j] = (bf16)b[j]; }
    *(bf16x8*)(wb + (size_t)m * 262144 + off) = o;
    return;
  }
  int wave = threadIdx.x >> 6, lane = threadIdx.x & 63;
  int row = blockIdx.x * 4 + wave;                 // 8192 rows
  const float* xr = x + (size_t)row * 512 + lane * 8;
  f32x4 v0 = *(const f32x4*)xr;
  f32x4 v1 = *(const f32x4*)(xr + 4);
  float f[8], s = 0.f, s2 = 0.f;
#pragma unroll
  for (int i = 0; i < 4; ++i) { f[i] = v0[i]; f[4 + i] = v1[i]; }
#pragma unroll
  for (int i = 0; i < 8; ++i) { s += f[i]; s2 += f[i] * f[i]; }
#pragma unroll
  for (int off = 1; off < 64; off <<= 1) {
    s  += __shfl_xor(s, off, 64);
    s2 += __shfl_xor(s2, off, 64);
  }
  float mu  = s * (1.f / 512.f);
  float var = s2 * (1.f / 512.f) - mu * mu;
  float rstd = rsqrtf(var + 1e-5f);
  f32x4 g0 = *(const f32x4*)(gamma + lane * 8);
  f32x4 g1 = *(const f32x4*)(gamma + lane * 8 + 4);
  f32x4 b0 = *(const f32x4*)(beta + lane * 8);
  f32x4 b1 = *(const f32x4*)(beta + lane * 8 + 4);
  bf16x8 o;
#pragma unroll
  for (int i = 0; i < 4; ++i) {
    o[i]     = (bf16)((f[i]     - mu) * rstd * g0[i] + b0[i]);
    o[4 + i] = (bf16)((f[4 + i] - mu) * rstd * g1[i] + b1[i]);
  }
  *(bf16x8*)(h + (size_t)row * 512 + lane * 8) = o;
}

// ------------------------------------------------------------- QKV GEMM
// Staging via gl_lds16 double-buffer: tile A/B = 128x64 bf16 (16KB each),
// 2 buffers = 64KB LDS. Pre-swizzled source reproduces the SW layout.
__global__ __launch_bounds__(256) void qkv_kernel(
    const bf16* __restrict__ h, const bf16* __restrict__ wb,
    bf16* __restrict__ Qg, bf16* __restrict__ Kg, bf16* __restrict__ Vtg) {
  __shared__ bf16 smemq[2 * 2 * 8192];   // [buf][A|B][8192] = 64KB
  int tid = threadIdx.x, wave = tid >> 6, lane = tid & 63;
  int wm = wave >> 1, wn = wave & 1, quad = lane >> 4, l15 = lane & 15;
  // XCD-chunked swizzle: XCD k owns mtiles [8k,8k+8) x all 12 (wsel,nb).
  int lin = blockIdx.x + (blockIdx.y << 6);        // 0..767
  int xcd = lin & 7, idx = lin >> 3;               // 96 blocks per XCD
  int mtile = xcd * 8 + idx / 12;                  // 0..63
  int yy = idx % 12;
  int wsel = yy >> 2;                              // 0=q 1=k 2=v
  int nb = yy & 3;
  const bf16* Abase = h + (size_t)mtile * 128 * 512;
  const bf16* Bbase = wb + (size_t)wsel * 262144 + (size_t)nb * 128 * 512;
  f32x4 acc[4][4];
#pragma unroll
  for (int i = 0; i < 4; ++i)
#pragma unroll
    for (int j = 0; j < 4; ++j) acc[i][j] = (f32x4){0.f, 0.f, 0.f, 0.f};

  // Per-thread pre-swizzled source offsets (same algebra as attn K staging):
  // linear LDS elem g -> row lr=g>>6, phys grp pg=(g>>3)&7 holds content
  // grp lg = pg^(lr&7): src = base + lr*512 + lg*8 (+k0 per tile).
  int g0 = wave * 2048 + lane * 8;
  int srcOff[4];
#pragma unroll
  for (int i = 0; i < 4; ++i) {
    int g = g0 + i * 512;
    int lr = g >> 6, lg = ((g >> 3) & 7) ^ (lr & 7);
    srcOff[i] = lr * 512 + lg * 8;
  }
  int dstOff = wave * 2048;              // wave-uniform; +i*512 per slot

  // prologue: tile 0 -> buf0
#pragma unroll
  for (int i = 0; i < 4; ++i) {
    gl_lds16(Abase + srcOff[i], smemq + dstOff + i * 512);
    gl_lds16(Bbase + srcOff[i], smemq + 8192 + dstOff + i * 512);
  }
  __syncthreads();                       // drains vmcnt: tile 0 visible

  for (int kt = 0; kt < 8; ++kt) {
    int cur = kt & 1;
    bf16* As = smemq + cur * 16384;
    bf16* Bs = As + 8192;
    if (kt < 7) {                        // issue tile kt+1 -> other buffer
      int nxt = cur ^ 1, k0n = (kt + 1) * 64;
      bf16* An = smemq + nxt * 16384;
#pragma unroll
      for (int i = 0; i < 4; ++i) {
        gl_lds16(Abase + k0n + srcOff[i], An + dstOff + i * 512);
        gl_lds16(Bbase + k0n + srcOff[i], An + 8192 + dstOff + i * 512);
      }
    }
#pragma unroll
    for (int c = 0; c < 2; ++c) {
      bf16x8 af[4], bw[4];
#pragma unroll
      for (int mt = 0; mt < 4; ++mt)
        af[mt] = *(const bf16x8*)(As + SW(wm * 64 + mt * 16 + l15, c * 4 + quad));
#pragma unroll
      for (int nt = 0; nt < 4; ++nt)
        bw[nt] = *(const bf16x8*)(Bs + SW(wn * 64 + nt * 16 + l15, c * 4 + quad));
#pragma unroll
      for (int mt = 0; mt < 4; ++mt)
#pragma unroll
        for (int nt = 0; nt < 4; ++nt)
          acc[mt][nt] = __builtin_amdgcn_mfma_f32_16x16x32_bf16(
              bw[nt], af[mt], acc[mt][nt], 0, 0, 0);
    }
    __syncthreads();   // drains vmcnt (kt+1) + readers done; swap buffers
  }
  // Q pre-scale folds softmax 1/sqrt(64) AND log2(e) for exp2-based softmax.
  if (wsel < 2) {
    float qscale = (wsel == 0) ? (0.125f * LOG2E) : 1.0f;
#pragma unroll
    for (int mt = 0; mt < 4; ++mt) {
      int m_g = mtile * 128 + wm * 64 + mt * 16 + l15;   // token
      int b = m_g >> 12, s = m_g & 4095;
#pragma unroll
      for (int nt = 0; nt < 4; ++nt) {
        int n_g = nb * 128 + wn * 64 + nt * 16 + quad * 4;  // feature
        int head = n_g >> 6, d = n_g & 63;
        f32x4 a = acc[mt][nt];
        bf16* dst = (wsel == 0 ? Qg : Kg) +
                    ((size_t)((b * 8 + head) * 4096 + s)) * 64 + d;
        bf16x4 pk;
#pragma unroll
        for (int r = 0; r < 4; ++r) pk[r] = (bf16)(a[r] * qscale);
        *(bf16x4*)dst = pk;
      }
    }
  } else {
    // V^T store in SLOT ORDER via LDS transpose. Vt[128 feat][128 tok]
    // (32KB alias over buf0), token col XOR-swizzled by (feat&7)<<3.
    bf16* Vt = smemq;
#pragma unroll
    for (int mt = 0; mt < 4; ++mt) {
      int t = wm * 64 + mt * 16 + l15;                     // token-local
#pragma unroll
      for (int nt = 0; nt < 4; ++nt) {
#pragma unroll
        for (int r = 0; r < 4; ++r) {
          int f = wn * 64 + nt * 16 + quad * 4 + r;        // feature-local
          Vt[f * 128 + (t ^ ((f & 7) << 3))] = (bf16)acc[mt][nt][r];
        }
      }
    }
    __syncthreads();
    int fr = tid >> 1, hf = tid & 1;
    int n_g = nb * 128 + fr;
    int head = n_g >> 6, d = n_g & 63;
    int bb = mtile >> 5;                                   // batch of block
    bf16* dst = Vtg + ((size_t)((bb * 8 + head) * 64 + d)) * 4096 +
                (mtile & 31) * 128 + hf * 64;
    int sx3 = (fr & 7) << 3;
#pragma unroll
    for (int g = 0; g < 8; ++g) {
      int pr = g >> 2, qd = g & 3;
      int tb = hf * 64 + pr * 32 + qd * 4;
      bf16x4 lo  = *(const bf16x4*)(Vt + fr * 128 + (tb ^ sx3));
      bf16x4 hi4 = *(const bf16x4*)(Vt + fr * 128 + ((tb + 16) ^ sx3));
      bf16x8 v;
#pragma unroll
      for (int j = 0; j < 4; ++j) { v[j] = lo[j]; v[4 + j] = hi4[j]; }
      *(bf16x8*)(dst + g * 8) = v;
    }
  }
}

// --------------------------------------------------------- Flash attention
// R19 structure (best, 71.5us): 4 waves = (qgrp 0/1) x (khalf 0/1). 64
// q/wave, keys [khalf*2048,+2048) in 32 tiles of 64. K/V dbuf (64KB), 1
// barrier/tile. Staging via global_load_lds w16 (pre-swizzled source).
__global__ __launch_bounds__(256, 2) void attn_kernel(
    const bf16* __restrict__ Qg, const bf16* __restrict__ Kg,
    const bf16* __restrict__ Vtg, bf16* __restrict__ Og) {
  __shared__ char smem[64 * 1024];
  bf16* KV = (bf16*)smem;               // [buf][khalf][K 4096 | V 4096]
  float* OL = (float*)smem;             // merge alias: 2x4096 f32
  float* Ll = (float*)(smem + 49152);   // merge l: 128 f32 (alias)

  int tid = threadIdx.x, wave = tid >> 6, lane = tid & 63;
  int quad = lane >> 4, l15 = lane & 15;
  int qgrp = wave & 1, khalf = wave >> 1;
  // XCD swizzle: XCD k serves bh pair {2k,2k+1}.
  int lin = blockIdx.x;                 // 0..511
  int bh = ((lin & 7) << 1) | ((lin >> 3) & 1);
  int q0 = (lin >> 4) * 128;
  int hi = bh & 7, bi = bh >> 3;
  const bf16* Kh  = Kg  + (size_t)bh * 4096 * 64;
  const bf16* Vth = Vtg + (size_t)bh * 64 * 4096;

  bf16x8 qf[4][2];   // Q pre-scaled by 0.125*LOG2E in qkv
#pragma unroll
  for (int mt = 0; mt < 4; ++mt)
#pragma unroll
    for (int c = 0; c < 2; ++c)
      qf[mt][c] = *(const bf16x8*)(
          Qg + ((size_t)bh * 4096 + q0 + qgrp * 64 + mt * 16 + l15) * 64 +
          c * 32 + quad * 8);

  f32x4 o_acc[4][4], lacc[4];
#pragma unroll
  for (int mt = 0; mt < 4; ++mt) {
    lacc[mt] = (f32x4){0.f, 0.f, 0.f, 0.f};
#pragma unroll
    for (int nt = 0; nt < 4; ++nt) o_acc[mt][nt] = (f32x4){0.f, 0.f, 0.f, 0.f};
  }
  const u32x4 onesu = {0x3F803F80u, 0x3F803F80u, 0x3F803F80u, 0x3F803F80u};
  const bf16x8 ones8 = __builtin_bit_cast(bf16x8, onesu);
  const f32x4 z4 = {0.f, 0.f, 0.f, 0.f};  // shared zero C-in for QK MFMAs

  // Staging: wave (qgrp,khalf) stages stream qgrp (0=K,1=V) of its khalf.
  // Pre-swizzled per-lane source: lane l covers LDS row lr=l>>3, phys grp
  // l&7 -> content grp lg=(l&7)^(lr&7).
  int key0 = khalf * 2048;
  int lr = lane >> 3, lg = (lane & 7) ^ (lr & 7);
  const bf16* gKb = Kh + ((size_t)key0 + lr) * 64 + lg * 8;   // +kt*4096+i*512
  const bf16* gVb = Vth + (size_t)lr * 4096 + key0 + lg * 8;  // +kt*64+i*32768
  bf16* myK = KV + khalf * 8192;        // dest in buf0
  bf16* myV = myK + 4096;

  if (qgrp == 0) {                       // tile 0 -> buf0
#pragma unroll
    for (int i = 0; i < 8; ++i) gl_lds16(gKb + i * 512, myK + i * 512);
  } else {
#pragma unroll
    for (int i = 0; i < 8; ++i)
      gl_lds16(gVb + (size_t)i * 32768, myV + i * 512);
  }
  __syncthreads();                       // drains vmcnt: tile 0 visible

  for (int kt = 0; kt < 32; ++kt) {
    int cur = kt & 1, nxt = cur ^ 1;
    bf16* Ksw = KV + cur * 16384 + khalf * 8192;
    bf16* Vsw = Ksw + 4096;
    if (kt < 31) {                       // issue tile kt+1 -> other buffer
      if (qgrp == 0) {
        const bf16* src = gKb + (size_t)(kt + 1) * 4096;
        bf16* d = myK + nxt * 16384;
#pragma unroll
        for (int i = 0; i < 8; ++i) gl_lds16(src + i * 512, d + i * 512);
      } else {
        const bf16* src = gVb + (kt + 1) * 64;
        bf16* d = myV + nxt * 16384;
#pragma unroll
        for (int i = 0; i < 8; ++i)
          gl_lds16(src + (size_t)i * 32768, d + i * 512);
      }
    }
    // ---- compute tile kt ----
    bf16x8 kf[8];
#pragma unroll
    for (int kb = 0; kb < 4; ++kb)
#pragma unroll
      for (int c = 0; c < 2; ++c)
        kf[kb * 2 + c] = *(const bf16x8*)(Ksw + SW(kb * 16 + l15, c * 4 + quad));
    bf16x8 vf8[2][4];
#pragma unroll
    for (int pr = 0; pr < 2; ++pr)
#pragma unroll
      for (int nt = 0; nt < 4; ++nt)
        vf8[pr][nt] = *(const bf16x8*)(Vsw + SW(nt * 16 + l15, pr * 4 + quad));
#pragma unroll
    for (int mt = 0; mt < 4; ++mt) {
      f32x4 st[4];
#pragma unroll
      for (int kb = 0; kb < 4; ++kb)     // c=0 slab: shared zero C-in
        st[kb] = __builtin_amdgcn_mfma_f32_16x16x32_bf16(
            kf[kb * 2], qf[mt][0], z4, 0, 0, 0);
#pragma unroll
      for (int kb = 0; kb < 4; ++kb)     // c=1 slab accumulates
        st[kb] = __builtin_amdgcn_mfma_f32_16x16x32_bf16(
            kf[kb * 2 + 1], qf[mt][1], st[kb], 0, 0, 0);
#pragma unroll
      for (int pr = 0; pr < 2; ++pr) {
        float ea[4], eb[4];
#pragma unroll
        for (int r = 0; r < 4; ++r) {
          ea[r] = __builtin_amdgcn_exp2f(st[pr * 2][r]);
          eb[r] = __builtin_amdgcn_exp2f(st[pr * 2 + 1][r]);
        }
        u32x4 pw = {pkbf16(ea[0], ea[1]), pkbf16(ea[2], ea[3]),
                    pkbf16(eb[0], eb[1]), pkbf16(eb[2], eb[3])};
        bf16x8 pk8 = __builtin_bit_cast(bf16x8, pw);
#pragma unroll
        for (int nt = 0; nt < 4; ++nt)
          o_acc[mt][nt] = __builtin_amdgcn_mfma_f32_16x16x32_bf16(
              vf8[pr][nt], pk8, o_acc[mt][nt], 0, 0, 0);
        lacc[mt] = __builtin_amdgcn_mfma_f32_16x16x32_bf16(
            ones8, pk8, lacc[mt], 0, 0, 0);
      }
    }
    __syncthreads();   // drains vmcnt (kt+1 writes) + lgkm; swap buffers
  }
  // ---- merge the two key-halves (pure addition; no-max softmax) ----
  if (khalf == 1) {
    float* dst = OL + qgrp * 4096;
#pragma unroll
    for (int mt = 0; mt < 4; ++mt) {
#pragma unroll
      for (int nt = 0; nt < 4; ++nt) {
        int row = mt * 16 + l15;
        int g = nt * 4 + quad;
        int gs = (g & 8) | ((g ^ row) & 7);
        *(f32x4*)(&dst[row * 64 + gs * 4]) = o_acc[mt][nt];
      }
      if (quad == 0) Ll[qgrp * 64 + mt * 16 + l15] = lacc[mt][0];
    }
  }
  __syncthreads();
  if (khalf == 0) {
    const float* src = OL + qgrp * 4096;
#pragma unroll
    for (int mt = 0; mt < 4; ++mt) {
      float lt = lacc[mt][0] + Ll[qgrp * 64 + mt * 16 + l15];
      float inv = 1.0f / lt;
      int q = q0 + qgrp * 64 + mt * 16 + l15;
#pragma unroll
      for (int nt = 0; nt < 4; ++nt) {
        int row = mt * 16 + l15;
        int g = nt * 4 + quad;
        int gs = (g & 8) | ((g ^ row) & 7);
        f32x4 o = *(const f32x4*)(&src[row * 64 + gs * 4]);
        bf16x4 pk;
#pragma unroll
        for (int r = 0; r < 4; ++r)
          pk[r] = (bf16)((o[r] + o_acc[mt][nt][r]) * inv);
        *(bf16x4*)(&Og[((size_t)bi * 4096 + q) * 512 + hi * 64 + nt * 16 +
                       quad * 4]) = pk;
      }
    }
  }
}

// ----------------------------------------------- out = A @ Wo^T + bo + x
// Same gl_lds16 double-buffer staging as qkv (Wo from bf16 buffer).
__global__ __launch_bounds__(256) void proj_kernel(
    const bf16* __restrict__ A, const bf16* __restrict__ wo_b,
    const float* __restrict__ bo, const float* __restrict__ x,
    float* __restrict__ out) {
  __shared__ bf16 smemq[2 * 2 * 8192];   // [buf][A|B][8192] = 64KB
  int tid = threadIdx.x, wave = tid >> 6, lane = tid & 63;
  int wm = wave >> 1, wn = wave & 1, quad = lane >> 4, l15 = lane & 15;
  int mtile = blockIdx.x, nb = blockIdx.y;
  const bf16* Abase = A + (size_t)mtile * 128 * 512;
  const bf16* Bbase = wo_b + (size_t)nb * 128 * 512;
  f32x4 acc[4][4];
#pragma unroll
  for (int i = 0; i < 4; ++i)
#pragma unroll
    for (int j = 0; j < 4; ++j) acc[i][j] = (f32x4){0.f, 0.f, 0.f, 0.f};

  int g0 = wave * 2048 + lane * 8;
  int srcOff[4];
#pragma unroll
  for (int i = 0; i < 4; ++i) {
    int g = g0 + i * 512;
    int lr = g >> 6, lg = ((g >> 3) & 7) ^ (lr & 7);
    srcOff[i] = lr * 512 + lg * 8;
  }
  int dstOff = wave * 2048;

#pragma unroll
  for (int i = 0; i < 4; ++i) {          // prologue: tile 0 -> buf0
    gl_lds16(Abase + srcOff[i], smemq + dstOff + i * 512);
    gl_lds16(Bbase + srcOff[i], smemq + 8192 + dstOff + i * 512);
  }
  __syncthreads();

  for (int kt = 0; kt < 8; ++kt) {
    int cur = kt & 1;
    bf16* As = smemq + cur * 16384;
    bf16* Bs = As + 8192;
    if (kt < 7) {
      int nxt = cur ^ 1, k0n = (kt + 1) * 64;
      bf16* An = smemq + nxt * 16384;
#pragma unroll
      for (int i = 0; i < 4; ++i) {
        gl_lds16(Abase + k0n + srcOff[i], An + dstOff + i * 512);
        gl_lds16(Bbase + k0n + srcOff[i], An + 8192 + dstOff + i * 512);
      }
    }
#pragma unroll
    for (int c = 0; c < 2; ++c) {
      bf16x8 af[4], bw[4];
#pragma unroll
      for (int mt = 0; mt < 4; ++mt)
        af[mt] = *(const bf16x8*)(As + SW(wm * 64 + mt * 16 + l15, c * 4 + quad));
#pragma unroll
      for (int nt = 0; nt < 4; ++nt)
        bw[nt] = *(const bf16x8*)(Bs + SW(wn * 64 + nt * 16 + l15, c * 4 + quad));
#pragma unroll
      for (int mt = 0; mt < 4; ++mt)
#pragma unroll
        for (int nt = 0; nt < 4; ++nt)
          acc[mt][nt] = __builtin_amdgcn_mfma_f32_16x16x32_bf16(
              bw[nt], af[mt], acc[mt][nt], 0, 0, 0);
    }
    __syncthreads();
  }
#pragma unroll
  for (int mt = 0; mt < 4; ++mt) {
    int m_g = mtile * 128 + wm * 64 + mt * 16 + l15;
#pragma unroll
    for (int nt = 0; nt < 4; ++nt) {
      int n_g = nb * 128 + wn * 64 + nt * 16 + quad * 4;
      f32x4 a = acc[mt][nt];
      f32x4 xr = *(const f32x4*)(x + (size_t)m_g * 512 + n_g);
      f32x4 bb = *(const f32x4*)(bo + n_g);
      f32x4 o;
#pragma unroll
      for (int r = 0; r < 4; ++r)
        o[r] = a[r] + bb[r] + xr[r];
      *(f32x4*)(out + (size_t)m_g * 512 + n_g) = o;
    }
  }
}

extern "C" void kernel_launch(void* const* d_in, const int* in_sizes, int n_in,
                              void* d_out, int out_size, void* d_ws, size_t ws_size,
                              hipStream_t stream) {
  const float* x     = (const float*)d_in[0];
  const float* wq    = (const float*)d_in[1];
  const float* wk    = (const float*)d_in[2];
  const float* wv    = (const float*)d_in[3];
  const float* wo    = (const float*)d_in[4];
  const float* bo    = (const float*)d_in[5];
  const float* gamma = (const float*)d_in[6];
  const float* beta  = (const float*)d_in[7];
  float* out = (float*)d_out;
  char* ws = (char*)d_ws;
  const size_t SZ = (size_t)8192 * 512 * sizeof(bf16);  // 8 MB
  bf16* h   = (bf16*)(ws);          // aliased with Ao (h dead before attn)
  bf16* Ao  = (bf16*)(ws);
  bf16* Qg  = (bf16*)(ws + SZ);
  bf16* Kg  = (bf16*)(ws + 2 * SZ);
  bf16* Vtg = (bf16*)(ws + 3 * SZ);
  bf16* wb  = (bf16*)(ws + 4 * SZ);  // 4 x 512KB bf16 weights

  ln_kernel<<<2560, 256, 0, stream>>>(x, gamma, beta, h, wq, wk, wv, wo, wb);
  qkv_kernel<<<dim3(64, 12), 256, 0, stream>>>(h, wb, Qg, Kg, Vtg);
  attn_kernel<<<512, 256, 0, stream>>>(Qg, Kg, Vtg, Ao);
  proj_kernel<<<dim3(64, 4), 256, 0, stream>>>(Ao, wb + 3 * 262144, bo, x, out);
}